// Round 1
// 547.698 us; speedup vs baseline: 1.0086x; 1.0086x over previous
//
#include <hip/hip_runtime.h>

// NeRF MLP, fully register-resident chain.
// Transposed MFMA formulation: D = A(W^T) * B(act^T), 16x16x32 f16.
//   A-frag: m=lane&15 (out feat), k=quad*8+j  (weights, pre-packed)
//   B-frag: n=lane&15 (point),   k=quad*8+j  (activations)
//   D     : col=lane&15 (point), row=quad*4+i (out feat)
// Feature ordering of every hidden layer is chosen so that D's registers,
// relu'd+converted, ARE the next layer's B-fragment (per-lane pack, no
// cross-lane movement). Hidden-layer feature at B slot (c,q,j) is the
// previous D's acc[2c + (j>>2)][j&3]  => logical feat phi = (2c+(j>>2))*16
// + q*4 + (j&3); weight packs below apply this permutation on both sides.
// Zero LDS; x loads land directly in B-slot order.
//
// R1 changes vs baseline (552.4 us):
//  - packrelu: relu moved AFTER the f32->f16 RTE convert (monotone round,
//    round(0)=0 => bit-identical results); 8x v_max_f32 replaced by
//    4x v_pk_max_f16 per call (10 calls/iter => ~40 VALU ops/iter saved).
//  - out store is non-temporal: out is write-once (33.5 MB/iter); keeping it
//    out of L2/L3 preserves Infinity-Cache residency of x across iterations.

typedef _Float16 half8  __attribute__((ext_vector_type(8)));
typedef float    floatx4 __attribute__((ext_vector_type(4)));

#define NPTS   2097152
#define NTILES (NPTS / 64)   // 4 waves/block, 16 pts per wave per tile

// ---------- weight pre-pack: 36 fragments x 64 lanes x 8 halfs -> d_ws ----
__global__ void prep_weights(const float* __restrict__ ws0, const float* __restrict__ ws1,
                             const float* __restrict__ ws2, const float* __restrict__ wc0,
                             const float* __restrict__ wc1, const float* __restrict__ wc2,
                             const float* __restrict__ wc3, _Float16* __restrict__ wpack) {
    int t = blockIdx.x * blockDim.x + threadIdx.x;
    if (t >= 36 * 64) return;
    int fid = t >> 6, lane = t & 63, l16 = lane & 15, q = lane >> 4;
#pragma unroll
    for (int j = 0; j < 8; ++j) {
        float v = 0.f;
        if (fid < 4) {                       // s0: natural input dims, mt=fid
            v = ws0[(q * 8 + j) * 64 + fid * 16 + l16];
        } else if (fid < 12) {               // s1: mt=(fid-4)>>1, c=(fid-4)&1
            int mt = (fid - 4) >> 1, c = (fid - 4) & 1;
            int p = (2 * c + (j >> 2)) * 16 + q * 4 + (j & 3);
            v = ws1[p * 64 + mt * 16 + l16];
        } else if (fid < 14) {               // s2: c=fid-12, 16 outs
            int c = fid - 12;
            int p = (2 * c + (j >> 2)) * 16 + q * 4 + (j & 3);
            v = ws2[p * 16 + l16];
        } else if (fid < 18) {               // c0: mt=fid-14; views j<4, geo j>=4
            int mt = fid - 14;
            if (j < 4) v = wc0[(q * 4 + j) * 64 + mt * 16 + l16];
            else {
                int g = q * 4 + (j - 4);     // geo feat index (0 => sigma slot, pad)
                v = (g == 0) ? 0.f : wc0[(15 + g) * 64 + mt * 16 + l16];
            }
        } else if (fid < 26) {               // c1
            int mt = (fid - 18) >> 1, c = (fid - 18) & 1;
            int p = (2 * c + (j >> 2)) * 16 + q * 4 + (j & 3);
            v = wc1[p * 64 + mt * 16 + l16];
        } else if (fid < 34) {               // c2
            int mt = (fid - 26) >> 1, c = (fid - 26) & 1;
            int p = (2 * c + (j >> 2)) * 16 + q * 4 + (j & 3);
            v = wc2[p * 64 + mt * 16 + l16];
        } else {                             // c3: c=fid-34, 3 outs (pad rows >=3)
            int c = fid - 34;
            int p = (2 * c + (j >> 2)) * 16 + q * 4 + (j & 3);
            v = (l16 < 3) ? wc3[p * 3 + l16] : 0.f;
        }
        wpack[t * 8 + j] = (_Float16)v;
    }
}

// relu AFTER the RTE convert: round is monotone and round(0)=0, so
// (half)max(x,0) == max((half)x, 0) bit-for-bit. 8x cvt + 4x v_pk_max_f16
// replaces 8x v_max_f32 + 8x cvt.
__device__ __forceinline__ half8 packrelu(floatx4 a, floatx4 b) {
    half8 r;
    r[0] = (_Float16)a[0]; r[1] = (_Float16)a[1];
    r[2] = (_Float16)a[2]; r[3] = (_Float16)a[3];
    r[4] = (_Float16)b[0]; r[5] = (_Float16)b[1];
    r[6] = (_Float16)b[2]; r[7] = (_Float16)b[3];
    const half8 z = {(_Float16)0.f, (_Float16)0.f, (_Float16)0.f, (_Float16)0.f,
                     (_Float16)0.f, (_Float16)0.f, (_Float16)0.f, (_Float16)0.f};
    return __builtin_elementwise_max(r, z);
}

__global__ __launch_bounds__(256, 2)
void nerf_fused(const float* __restrict__ x, const _Float16* __restrict__ wpack,
                float* __restrict__ out) {
    const int lane = threadIdx.x & 63;
    const int w    = threadIdx.x >> 6;
    const int l16  = lane & 15;
    const int q    = lane >> 4;

    // 36 weight A-fragments -> registers (coalesced b128 loads)
    half8 W[36];
    const half8* wp = (const half8*)wpack;
#pragma unroll
    for (int f = 0; f < 36; ++f) W[f] = wp[f * 64 + lane];

    const floatx4 vz = {0.f, 0.f, 0.f, 0.f};
    const float4* xb = (const float4*)x;

    int tile = blockIdx.x;
    float4 vA, vB, vC;
    {
        size_t base = (size_t)(tile * 64 + w * 16 + l16) * 12;
        vA = xb[base + q * 2]; vB = xb[base + q * 2 + 1]; vC = xb[base + 8 + q];
    }

    while (tile < NTILES) {
        int next = tile + gridDim.x;
        int pf = next < NTILES ? next : tile;
        size_t nbase = (size_t)(pf * 64 + w * 16 + l16) * 12;
        float4 nA = xb[nbase + q * 2], nB = xb[nbase + q * 2 + 1], nC = xb[nbase + 8 + q];

        // ---- s0: B directly from x (dims q*8..q*8+7), K=32 ----
        half8 b0, b1;
        b0[0] = (_Float16)vA.x; b0[1] = (_Float16)vA.y; b0[2] = (_Float16)vA.z; b0[3] = (_Float16)vA.w;
        b0[4] = (_Float16)vB.x; b0[5] = (_Float16)vB.y; b0[6] = (_Float16)vB.z; b0[7] = (_Float16)vB.w;
        floatx4 acc[4], a2[4];
#pragma unroll
        for (int mt = 0; mt < 4; ++mt)
            acc[mt] = __builtin_amdgcn_mfma_f32_16x16x32_f16(W[mt], b0, vz, 0, 0, 0);

        // ---- s1 ----
        b0 = packrelu(acc[0], acc[1]); b1 = packrelu(acc[2], acc[3]);
#pragma unroll
        for (int mt = 0; mt < 4; ++mt) {
            a2[mt] = __builtin_amdgcn_mfma_f32_16x16x32_f16(W[4 + mt * 2], b0, vz,     0, 0, 0);
            a2[mt] = __builtin_amdgcn_mfma_f32_16x16x32_f16(W[5 + mt * 2], b1, a2[mt], 0, 0, 0);
        }

        // ---- s2 (no relu): sigma = feat0, geo = feats 1..15 ----
        b0 = packrelu(a2[0], a2[1]); b1 = packrelu(a2[2], a2[3]);
        floatx4 accS;
        accS = __builtin_amdgcn_mfma_f32_16x16x32_f16(W[12], b0, vz,   0, 0, 0);
        accS = __builtin_amdgcn_mfma_f32_16x16x32_f16(W[13], b1, accS, 0, 0, 0);
        float sigma = accS[0];   // valid in quad 0 lanes (pt = l16)

        // ---- c0: B = {views q*4..q*4+3 from vC, geo from accS}, K=32 ----
        half8 bc;
        bc[0] = (_Float16)vC.x; bc[1] = (_Float16)vC.y; bc[2] = (_Float16)vC.z; bc[3] = (_Float16)vC.w;
        bc[4] = (q == 0) ? (_Float16)0.f : (_Float16)accS[0];
        bc[5] = (_Float16)accS[1]; bc[6] = (_Float16)accS[2]; bc[7] = (_Float16)accS[3];
#pragma unroll
        for (int mt = 0; mt < 4; ++mt)
            acc[mt] = __builtin_amdgcn_mfma_f32_16x16x32_f16(W[14 + mt], bc, vz, 0, 0, 0);

        // ---- c1 ----
        b0 = packrelu(acc[0], acc[1]); b1 = packrelu(acc[2], acc[3]);
#pragma unroll
        for (int mt = 0; mt < 4; ++mt) {
            a2[mt] = __builtin_amdgcn_mfma_f32_16x16x32_f16(W[18 + mt * 2], b0, vz,     0, 0, 0);
            a2[mt] = __builtin_amdgcn_mfma_f32_16x16x32_f16(W[19 + mt * 2], b1, a2[mt], 0, 0, 0);
        }

        // ---- c2 ----
        b0 = packrelu(a2[0], a2[1]); b1 = packrelu(a2[2], a2[3]);
#pragma unroll
        for (int mt = 0; mt < 4; ++mt) {
            acc[mt] = __builtin_amdgcn_mfma_f32_16x16x32_f16(W[26 + mt * 2], b0, vz,      0, 0, 0);
            acc[mt] = __builtin_amdgcn_mfma_f32_16x16x32_f16(W[27 + mt * 2], b1, acc[mt], 0, 0, 0);
        }

        // ---- c3 (no relu, 3 outs) ----
        b0 = packrelu(acc[0], acc[1]); b1 = packrelu(acc[2], acc[3]);
        floatx4 accC;
        accC = __builtin_amdgcn_mfma_f32_16x16x32_f16(W[34], b0, vz,   0, 0, 0);
        accC = __builtin_amdgcn_mfma_f32_16x16x32_f16(W[35], b1, accC, 0, 0, 0);

        // ---- store: quad-0 lanes hold color rows 0..2 + sigma for pt=l16 ----
        // Non-temporal: out is write-once; don't evict x from L2/L3.
        if (lane < 16) {
            floatx4 o;
            o[0] = accC[0]; o[1] = accC[1]; o[2] = accC[2]; o[3] = sigma;
            __builtin_nontemporal_store(o, (floatx4*)out + ((size_t)tile * 64 + w * 16 + lane));
        }

        vA = nA; vB = nB; vC = nC;
        tile = next;
    }
}

extern "C" void kernel_launch(void* const* d_in, const int* in_sizes, int n_in,
                              void* d_out, int out_size, void* d_ws, size_t ws_size,
                              hipStream_t stream) {
    _Float16* wpack = (_Float16*)d_ws;  // 36*64*8 halfs = 36 KB
    prep_weights<<<9, 256, 0, stream>>>(
        (const float*)d_in[1], (const float*)d_in[2], (const float*)d_in[3],
        (const float*)d_in[4], (const float*)d_in[5], (const float*)d_in[6],
        (const float*)d_in[7], wpack);
    nerf_fused<<<1024, 256, 0, stream>>>((const float*)d_in[0], wpack, (float*)d_out);
}